// Round 19
// baseline (139.063 us; speedup 1.0000x reference)
//
#include <hip/hip_runtime.h>
#include <math.h>

// GIN 2-layer, round 19: R18 +
//  - bucket_scatter: direct scattered write (no block-local scan / LDS pack / copy-out)
//  - final_fused: uint2 gathers (lane = nsel|es2|q3, 5 valid q), agg1's pattern
//  prep -> bucket_scatter -> bucket_csr -> agg1 -> gemm12 -> final_fused

#define IN_DIM 64
#define HID_DIM 128
#define OUT_DIM 40

#define BSH 8
#define MAXNB 512
#define EPB 4096
#define CAP 5120      // per-bucket staging capacity (mean 4096 -> +16 sigma)
#define H1S 136       // LDS h1 row stride in bf16
#define EPT 16        // edges per thread in bucket_scatter (EPB/256)
#define CPT 20        // max entries per thread in bucket_csr (CAP/256)

typedef unsigned short ushort;
typedef unsigned char uchar;
typedef unsigned int uint;
typedef float floatx2 __attribute__((ext_vector_type(2)));
typedef short short8_t __attribute__((ext_vector_type(8)));   // 8 bf16 (4 VGPRs)
typedef float float4_t __attribute__((ext_vector_type(4)));   // MFMA acc

__device__ __forceinline__ ushort f2bf(float f) {
  unsigned u = __float_as_uint(f);
  u += 0x7fffu + ((u >> 16) & 1u);
  return (ushort)(u >> 16);
}

// ------- prep: x -> fp8 x8 (64B rows), W1T/W2T bf16 transpose, gcur = 0 -------

__global__ __launch_bounds__(256) void prep(
    const float4* __restrict__ x4, uint2* __restrict__ x8, int n8,
    const float* __restrict__ W1, const float* __restrict__ W2,
    ushort* __restrict__ W1T, ushort* __restrict__ W2T, int* __restrict__ gcur) {
  int id = blockIdx.x * 256 + threadIdx.x;
  if (id < n8) {
    float4 a = x4[2 * id], b = x4[2 * id + 1];
    int p0 = __builtin_amdgcn_cvt_pk_fp8_f32(a.x, a.y, 0, false);
    p0 = __builtin_amdgcn_cvt_pk_fp8_f32(a.z, a.w, p0, true);
    int p1 = __builtin_amdgcn_cvt_pk_fp8_f32(b.x, b.y, 0, false);
    p1 = __builtin_amdgcn_cvt_pk_fp8_f32(b.z, b.w, p1, true);
    x8[id] = (uint2){(uint)p0, (uint)p1};
  }
  if (id < HID_DIM * IN_DIM) {             // 8192
    int c = id / IN_DIM, k = id - c * IN_DIM;
    W1T[id] = f2bf(W1[k * HID_DIM + c]);
  }
  if (id < 48 * HID_DIM) {                 // 6144
    int c = id / HID_DIM, k = id - c * HID_DIM;
    W2T[id] = (c < OUT_DIM) ? f2bf(W2[k * OUT_DIM + c]) : 0;
  }
  if (id < MAXNB) gcur[id] = 0;
}

// ------- bucket_scatter: reg-cached edges -> direct write into bucket staging -------

__global__ __launch_bounds__(256) void bucket_scatter(
    const int* __restrict__ src, const int* __restrict__ dst,
    int* __restrict__ gcur, int* __restrict__ epk_s, int n_edges, int nb) {
  __shared__ int hist[MAXNB];
  __shared__ int lofs[MAXNB];
  __shared__ int gbase[MAXNB];
  int tid = threadIdx.x;
  for (int i = tid; i < nb; i += 256) { hist[i] = 0; lofs[i] = 0; }
  __syncthreads();
  int e0 = blockIdx.x * EPB;
  int cnt = min(EPB, n_edges - e0);
  int dr[EPT], sr[EPT];
#pragma unroll
  for (int r = 0; r < EPT; ++r) {        // single read pass, cached in regs
    int i = r * 256 + tid;
    if (i < cnt) {
      dr[r] = dst[e0 + i];
      sr[r] = src[e0 + i];
      atomicAdd(&hist[dr[r] >> BSH], 1);
    } else { dr[r] = -1; sr[r] = 0; }
  }
  __syncthreads();
  for (int i = tid; i < nb; i += 256)
    if (hist[i]) gbase[i] = atomicAdd(&gcur[i], hist[i]);
  __syncthreads();
#pragma unroll
  for (int r = 0; r < EPT; ++r) {        // direct scattered write (10-entry runs/bucket)
    if (dr[r] >= 0) {
      int b = dr[r] >> BSH;
      int p = gbase[b] + atomicAdd(&lofs[b], 1);
      epk_s[b * CAP + p] = ((dr[r] & 255) << 17) | sr[r];   // n_nodes < 2^17
    }
  }
}

// ------- bucket_csr: reg-cached epk -> off2{start,end} + sorted esrc -------

__global__ __launch_bounds__(256) void bucket_csr(
    const int* __restrict__ epk_s, const int* __restrict__ gcnt,
    int2* __restrict__ off2, int* __restrict__ esrc_s, int n_nodes) {
  __shared__ int hist[256];
  __shared__ int cur[256];
  int b = blockIdx.x;
  int base = b * CAP;
  int cnt = gcnt[b];
  int nb0 = b << BSH;
  int nn = min(256, n_nodes - nb0);
  int tid = threadIdx.x;
  hist[tid] = 0;
  __syncthreads();
  int pv[CPT];
#pragma unroll
  for (int r = 0; r < CPT; ++r) {        // single read pass, cached in regs
    int i = r * 256 + tid;
    if (i < cnt) {
      pv[r] = epk_s[base + i];
      atomicAdd(&hist[pv[r] >> 17], 1);
    } else pv[r] = -1;
  }
  __syncthreads();
  if (tid < 64) {  // exclusive scan of 256 entries
    int carry = 0;
#pragma unroll
    for (int c = 0; c < 256; c += 64) {
      int v = hist[c + tid];
      int incl = v;
#pragma unroll
      for (int d = 1; d < 64; d <<= 1) {
        int t = __shfl_up(incl, d, 64);
        if (tid >= d) incl += t;
      }
      cur[c + tid] = carry + incl - v;
      carry += __shfl(incl, 63, 64);
    }
  }
  __syncthreads();
  if (tid < nn) {
    int st = cur[tid];
    off2[nb0 + tid] = make_int2(base + st, base + st + hist[tid]);
  }
  __syncthreads();  // off2 reads cur/hist before scatter mutates cur
#pragma unroll
  for (int r = 0; r < CPT; ++r) {
    if (pv[r] >= 0) {
      int pos = atomicAdd(&cur[pv[r] >> 17], 1);
      esrc_s[base + pos] = pv[r] & 0x1FFFF;
    }
  }
}

// -------- agg1: aggr1h[n] = bf16(x[n] + sum_j x8[j]), 2 nodes/wave, uint2 loads --------
// lane: bit5 = node-select, bits3-4 = edge-slot (4), bits0-2 = uint2 q of 64B row.

__global__ __launch_bounds__(256) void agg1(
    const float4* __restrict__ x4, const uint2* __restrict__ x8,
    const int2* __restrict__ off2, const int* __restrict__ esrc,
    ushort* __restrict__ aggrh, int n_nodes) {
  int tid = threadIdx.x;
  int lane = tid & 63;
  int nsel = (lane >> 5) & 1, es = (lane >> 3) & 3, q = lane & 7;
  int node = blockIdx.x * 8 + (tid >> 6) * 2 + nsel;
  bool nok = node < n_nodes;
  int2 oe = nok ? off2[node] : make_int2(0, 0);
  floatx2 A0 = {0.f, 0.f}, A1 = {0.f, 0.f}, A2 = {0.f, 0.f}, A3 = {0.f, 0.f};
  floatx2 C0 = {0.f, 0.f}, C1 = {0.f, 0.f}, C2 = {0.f, 0.f}, C3 = {0.f, 0.f};
  int e = oe.x, end = oe.y;
  for (; e + 8 <= end; e += 8) {           // 8 edges, 2 loads/lane
    uint2 u0 = x8[(uint)(esrc[e + es] * 8 + q)];
    uint2 u1 = x8[(uint)(esrc[e + 4 + es] * 8 + q)];
    A0 += __builtin_amdgcn_cvt_pk_f32_fp8((int)u0.x, false);
    A1 += __builtin_amdgcn_cvt_pk_f32_fp8((int)u0.x, true);
    A2 += __builtin_amdgcn_cvt_pk_f32_fp8((int)u0.y, false);
    A3 += __builtin_amdgcn_cvt_pk_f32_fp8((int)u0.y, true);
    C0 += __builtin_amdgcn_cvt_pk_f32_fp8((int)u1.x, false);
    C1 += __builtin_amdgcn_cvt_pk_f32_fp8((int)u1.x, true);
    C2 += __builtin_amdgcn_cvt_pk_f32_fp8((int)u1.y, false);
    C3 += __builtin_amdgcn_cvt_pk_f32_fp8((int)u1.y, true);
  }
  for (; e < end; e += 4) {
    int idx = e + es;
    if (idx < end) {
      uint2 u = x8[(uint)(esrc[idx] * 8 + q)];
      A0 += __builtin_amdgcn_cvt_pk_f32_fp8((int)u.x, false);
      A1 += __builtin_amdgcn_cvt_pk_f32_fp8((int)u.x, true);
      A2 += __builtin_amdgcn_cvt_pk_f32_fp8((int)u.y, false);
      A3 += __builtin_amdgcn_cvt_pk_f32_fp8((int)u.y, true);
    }
  }
  A0 += C0; A1 += C1; A2 += C2; A3 += C3;
  // reduce over edge-slot bits 3,4
#pragma unroll
  for (int d = 8; d <= 16; d <<= 1) {
    floatx2 t0, t1, t2, t3;
    t0[0] = __shfl_xor(A0[0], d, 64); t0[1] = __shfl_xor(A0[1], d, 64);
    t1[0] = __shfl_xor(A1[0], d, 64); t1[1] = __shfl_xor(A1[1], d, 64);
    t2[0] = __shfl_xor(A2[0], d, 64); t2[1] = __shfl_xor(A2[1], d, 64);
    t3[0] = __shfl_xor(A3[0], d, 64); t3[1] = __shfl_xor(A3[1], d, 64);
    A0 += t0; A1 += t1; A2 += t2; A3 += t3;
  }
  if (nok) {  // self row (fp32) for features 8q..8q+7
    float4 xa = x4[(uint)(node * 16 + q * 2)];
    float4 xb = x4[(uint)(node * 16 + q * 2 + 1)];
    A0 += (floatx2){xa.x, xa.y};
    A1 += (floatx2){xa.z, xa.w};
    A2 += (floatx2){xb.x, xb.y};
    A3 += (floatx2){xb.z, xb.w};
  }
  if (nok && es == 0) {
    uint4 o;
    o.x = (uint)f2bf(A0[0]) | ((uint)f2bf(A0[1]) << 16);
    o.y = (uint)f2bf(A1[0]) | ((uint)f2bf(A1[1]) << 16);
    o.z = (uint)f2bf(A2[0]) | ((uint)f2bf(A2[1]) << 16);
    o.w = (uint)f2bf(A3[0]) | ((uint)f2bf(A3[1]) << 16);
    ((uint4*)aggrh)[(uint)(node * 8 + q)] = o;
  }
}

// ------- gemm12 (MFMA, fused): th8 = fp8((relu(aggr@W1+b1)) @ W2), h1 in LDS -------

__global__ __launch_bounds__(256) void gemm12_mfma(
    const ushort* __restrict__ aggrh, const ushort* __restrict__ W1T,
    const float* __restrict__ b1, const ushort* __restrict__ W2T,
    uchar* __restrict__ th8, int n_nodes) {
  __shared__ ushort h1s[64 * H1S];
  int w = threadIdx.x >> 6, lane = threadIdx.x & 63;
  int n0 = blockIdx.x * 64 + w * 16;
  int row = lane & 15, kg = lane >> 4;
  int n = n0 + row;
  // ---- layer 1 ----
  {
    short8_t a0 = {}, a1 = {};
    if (n < n_nodes) {
      a0 = *(const short8_t*)&aggrh[(size_t)n * IN_DIM + kg * 8];
      a1 = *(const short8_t*)&aggrh[(size_t)n * IN_DIM + 32 + kg * 8];
    }
    float4_t acc[8];
#pragma unroll
    for (int ct = 0; ct < 8; ++ct) acc[ct] = (float4_t){0.f, 0.f, 0.f, 0.f};
#pragma unroll
    for (int ct = 0; ct < 8; ++ct) {
      int c = ct * 16 + row;
      short8_t b0 = *(const short8_t*)&W1T[(size_t)c * IN_DIM + kg * 8];
      short8_t b1f = *(const short8_t*)&W1T[(size_t)c * IN_DIM + 32 + kg * 8];
      acc[ct] = __builtin_amdgcn_mfma_f32_16x16x32_bf16(a0, b0, acc[ct], 0, 0, 0);
      acc[ct] = __builtin_amdgcn_mfma_f32_16x16x32_bf16(a1, b1f, acc[ct], 0, 0, 0);
    }
#pragma unroll
    for (int ct = 0; ct < 8; ++ct) {
      int j = ct * 16 + row;
      float bias = b1[j];
#pragma unroll
      for (int i = 0; i < 4; ++i) {
        int nl = w * 16 + kg * 4 + i;
        h1s[nl * H1S + j] = f2bf(fmaxf(acc[ct][i] + bias, 0.f));
      }
    }
  }
  __syncthreads();
  // ---- layer 2 (A from LDS h1s) ----
  {
    short8_t a[4];
#pragma unroll
    for (int ks = 0; ks < 4; ++ks)
      a[ks] = *(const short8_t*)&h1s[(w * 16 + row) * H1S + ks * 32 + kg * 8];
    float4_t acc[3];
#pragma unroll
    for (int ct = 0; ct < 3; ++ct) acc[ct] = (float4_t){0.f, 0.f, 0.f, 0.f};
#pragma unroll
    for (int ct = 0; ct < 3; ++ct) {
      int c = ct * 16 + row;
#pragma unroll
      for (int ks = 0; ks < 4; ++ks) {
        short8_t b = *(const short8_t*)&W2T[(size_t)c * HID_DIM + ks * 32 + kg * 8];
        acc[ct] = __builtin_amdgcn_mfma_f32_16x16x32_bf16(a[ks], b, acc[ct], 0, 0, 0);
      }
    }
#pragma unroll
    for (int ct = 0; ct < 3; ++ct) {
      int j = ct * 16 + row;
      if (j < OUT_DIM) {
#pragma unroll
        for (int i = 0; i < 4; ++i) {
          int nn = n0 + kg * 4 + i;
          if (nn < n_nodes) {
            int pk = __builtin_amdgcn_cvt_pk_fp8_f32(acc[ct][i], acc[ct][i], 0, false);
            th8[(size_t)nn * 40 + j] = (uchar)(pk & 0xff);
          }
        }
      }
    }
  }
}

// ------- final: out = log_softmax(t[n] + sum_j t[j] + b2), uint2 gathers -------
// lane: bit5 = node-select, bits3-4 = edge-slot (4), bits0-2 = uint2 q (valid q<5).

__global__ __launch_bounds__(256) void final_fused(
    const uchar* __restrict__ th8, const int2* __restrict__ off2,
    const int* __restrict__ esrc, const float* __restrict__ b2,
    float* __restrict__ out, int n_nodes) {
  int tid = threadIdx.x;
  int lane = tid & 63;
  int nsel = (lane >> 5) & 1, es = (lane >> 3) & 3, q = lane & 7;
  int node = blockIdx.x * 8 + (tid >> 6) * 2 + nsel;
  bool nok = node < n_nodes;
  bool valid = nok && (q < 5);
  const uint2* tr2 = (const uint2*)th8;   // row = 5 uint2 (40 B)
  int2 oe = nok ? off2[node] : make_int2(0, 0);
  uint2 uown = {0, 0};
  float4 bb0 = {0.f, 0.f, 0.f, 0.f}, bb1 = {0.f, 0.f, 0.f, 0.f};
  if (valid) {
    uown = tr2[(uint)(node * 5 + q)];
    bb0 = ((const float4*)b2)[2 * q];
    bb1 = ((const float4*)b2)[2 * q + 1];
  }
  floatx2 A0 = {0.f, 0.f}, A1 = {0.f, 0.f}, A2 = {0.f, 0.f}, A3 = {0.f, 0.f};
  floatx2 C0 = {0.f, 0.f}, C1 = {0.f, 0.f}, C2 = {0.f, 0.f}, C3 = {0.f, 0.f};
  int e = oe.x, end = oe.y;
  for (; e + 8 <= end; e += 8) {           // 8 edges, 2 uint2 loads/lane
    uint2 u0 = {0, 0}, u1 = {0, 0};
    if (valid) {
      u0 = tr2[(uint)(esrc[e + es] * 5 + q)];
      u1 = tr2[(uint)(esrc[e + 4 + es] * 5 + q)];
    }
    A0 += __builtin_amdgcn_cvt_pk_f32_fp8((int)u0.x, false);
    A1 += __builtin_amdgcn_cvt_pk_f32_fp8((int)u0.x, true);
    A2 += __builtin_amdgcn_cvt_pk_f32_fp8((int)u0.y, false);
    A3 += __builtin_amdgcn_cvt_pk_f32_fp8((int)u0.y, true);
    C0 += __builtin_amdgcn_cvt_pk_f32_fp8((int)u1.x, false);
    C1 += __builtin_amdgcn_cvt_pk_f32_fp8((int)u1.x, true);
    C2 += __builtin_amdgcn_cvt_pk_f32_fp8((int)u1.y, false);
    C3 += __builtin_amdgcn_cvt_pk_f32_fp8((int)u1.y, true);
  }
  for (; e < end; e += 4) {
    int idx = e + es;
    if (idx < end && valid) {
      uint2 u = tr2[(uint)(esrc[idx] * 5 + q)];
      A0 += __builtin_amdgcn_cvt_pk_f32_fp8((int)u.x, false);
      A1 += __builtin_amdgcn_cvt_pk_f32_fp8((int)u.x, true);
      A2 += __builtin_amdgcn_cvt_pk_f32_fp8((int)u.y, false);
      A3 += __builtin_amdgcn_cvt_pk_f32_fp8((int)u.y, true);
    }
  }
  A0 += C0; A1 += C1; A2 += C2; A3 += C3;
  // reduce over edge-slot bits 3,4
#pragma unroll
  for (int d = 8; d <= 16; d <<= 1) {
    floatx2 t0, t1, t2, t3;
    t0[0] = __shfl_xor(A0[0], d, 64); t0[1] = __shfl_xor(A0[1], d, 64);
    t1[0] = __shfl_xor(A1[0], d, 64); t1[1] = __shfl_xor(A1[1], d, 64);
    t2[0] = __shfl_xor(A2[0], d, 64); t2[1] = __shfl_xor(A2[1], d, 64);
    t3[0] = __shfl_xor(A3[0], d, 64); t3[1] = __shfl_xor(A3[1], d, 64);
    A0 += t0; A1 += t1; A2 += t2; A3 += t3;
  }
  // own row + bias (features 8q..8q+7)
  A0 += __builtin_amdgcn_cvt_pk_f32_fp8((int)uown.x, false);
  A1 += __builtin_amdgcn_cvt_pk_f32_fp8((int)uown.x, true);
  A2 += __builtin_amdgcn_cvt_pk_f32_fp8((int)uown.y, false);
  A3 += __builtin_amdgcn_cvt_pk_f32_fp8((int)uown.y, true);
  A0 += (floatx2){bb0.x, bb0.y};
  A1 += (floatx2){bb0.z, bb0.w};
  A2 += (floatx2){bb1.x, bb1.y};
  A3 += (floatx2){bb1.z, bb1.w};
  // softmax over 40 feats: (q<5) x 8 regs; reduce lane bits 0-2
  float m = valid ? fmaxf(fmaxf(fmaxf(A0[0], A0[1]), fmaxf(A1[0], A1[1])),
                          fmaxf(fmaxf(A2[0], A2[1]), fmaxf(A3[0], A3[1])))
                  : -INFINITY;
#pragma unroll
  for (int d = 1; d <= 4; d <<= 1) m = fmaxf(m, __shfl_xor(m, d, 64));
  float ssum = 0.f;
  if (valid)
    ssum = ((__expf(A0[0] - m) + __expf(A0[1] - m)) +
            (__expf(A1[0] - m) + __expf(A1[1] - m))) +
           ((__expf(A2[0] - m) + __expf(A2[1] - m)) +
            (__expf(A3[0] - m) + __expf(A3[1] - m)));
#pragma unroll
  for (int d = 1; d <= 4; d <<= 1) ssum += __shfl_xor(ssum, d, 64);
  if (valid && es == 0) {
    float ls = m + __logf(ssum);
    float4 o0 = {A0[0] - ls, A0[1] - ls, A1[0] - ls, A1[1] - ls};
    float4 o1 = {A2[0] - ls, A2[1] - ls, A3[0] - ls, A3[1] - ls};
    ((float4*)out)[(uint)(node * 10 + 2 * q)] = o0;
    ((float4*)out)[(uint)(node * 10 + 2 * q + 1)] = o1;
  }
}

// ---------------- launch ----------------

static inline char* align256(char* p) {
  return (char*)(((uintptr_t)p + 255) & ~(uintptr_t)255);
}

extern "C" void kernel_launch(void* const* d_in, const int* in_sizes, int n_in,
                              void* d_out, int out_size, void* d_ws, size_t ws_size,
                              hipStream_t stream) {
  const float* x  = (const float*)d_in[0];
  const int*   ei = (const int*)d_in[1];    // [2][E] int32
  const float* W1 = (const float*)d_in[2];
  const float* b1 = (const float*)d_in[3];
  const float* W2 = (const float*)d_in[4];
  const float* b2 = (const float*)d_in[5];
  float* out = (float*)d_out;

  int n_nodes = in_sizes[0] / IN_DIM;
  int n_edges = in_sizes[1] / 2;
  const int* src = ei;
  const int* dst = ei + n_edges;
  int nb = (n_nodes + 255) >> BSH;

  char* p = (char*)d_ws;
  int* gcur   = (int*)p;            p += MAXNB * 4;
  int2* off2  = (int2*)p;           p += (size_t)n_nodes * 8;
  p = align256(p);
  int* epk_s  = (int*)p;            p += (size_t)nb * CAP * 4;
  int* esrc_s = (int*)p;            p += (size_t)nb * CAP * 4;
  p = align256(p);
  uchar* x8    = (uchar*)p;         p += (size_t)n_nodes * IN_DIM;      // fp8, 64 B rows
  p = align256(p);
  ushort* aggrh = (ushort*)p;       p += (size_t)n_nodes * IN_DIM * 2;
  p = align256(p);
  uchar* th8    = (uchar*)p;        p += (size_t)n_nodes * 40 + 256;    // fp8, 40 B rows
  p = align256(p);
  ushort* W1T   = (ushort*)p;       p += HID_DIM * IN_DIM * 2;          // [128][64]
  ushort* W2T   = (ushort*)p;       p += 48 * HID_DIM * 2;              // [48][128]

  int n8 = n_nodes * IN_DIM / 8;
  prep<<<(n8 + 255) / 256, 256, 0, stream>>>(
      (const float4*)x, (uint2*)x8, n8, W1, W2, W1T, W2T, gcur);

  int egrid = (n_edges + EPB - 1) / EPB;
  bucket_scatter<<<egrid, 256, 0, stream>>>(src, dst, gcur, epk_s, n_edges, nb);
  bucket_csr<<<nb, 256, 0, stream>>>(epk_s, gcur, off2, esrc_s, n_nodes);

  agg1<<<(n_nodes + 7) / 8, 256, 0, stream>>>(
      (const float4*)x, (const uint2*)x8, off2, esrc_s, aggrh, n_nodes);
  int ggrid = (n_nodes + 63) / 64;
  gemm12_mfma<<<ggrid, 256, 0, stream>>>(aggrh, W1T, b1, W2T, th8, n_nodes);
  final_fused<<<(n_nodes + 7) / 8, 256, 0, stream>>>(th8, off2, esrc_s, b2, out, n_nodes);
}

// Round 20
// 137.372 us; speedup vs baseline: 1.0123x; 1.0123x over previous
//
#include <hip/hip_runtime.h>
#include <math.h>

// GIN 2-layer, round 20: R19 + final_fused re-mapped to 6 edge-slots x 5 uint2
// per node-half (94% lane utilization in the gather loop, 12 edges/iter).
//  prep -> bucket_scatter -> bucket_csr -> agg1 -> gemm12 -> final_fused

#define IN_DIM 64
#define HID_DIM 128
#define OUT_DIM 40

#define BSH 8
#define MAXNB 512
#define EPB 4096
#define CAP 5120      // per-bucket staging capacity (mean 4096 -> +16 sigma)
#define H1S 136       // LDS h1 row stride in bf16
#define EPT 16        // edges per thread in bucket_scatter (EPB/256)
#define CPT 20        // max entries per thread in bucket_csr (CAP/256)

typedef unsigned short ushort;
typedef unsigned char uchar;
typedef unsigned int uint;
typedef float floatx2 __attribute__((ext_vector_type(2)));
typedef short short8_t __attribute__((ext_vector_type(8)));   // 8 bf16 (4 VGPRs)
typedef float float4_t __attribute__((ext_vector_type(4)));   // MFMA acc

__device__ __forceinline__ ushort f2bf(float f) {
  unsigned u = __float_as_uint(f);
  u += 0x7fffu + ((u >> 16) & 1u);
  return (ushort)(u >> 16);
}

// ------- prep: x -> fp8 x8 (64B rows), W1T/W2T bf16 transpose, gcur = 0 -------

__global__ __launch_bounds__(256) void prep(
    const float4* __restrict__ x4, uint2* __restrict__ x8, int n8,
    const float* __restrict__ W1, const float* __restrict__ W2,
    ushort* __restrict__ W1T, ushort* __restrict__ W2T, int* __restrict__ gcur) {
  int id = blockIdx.x * 256 + threadIdx.x;
  if (id < n8) {
    float4 a = x4[2 * id], b = x4[2 * id + 1];
    int p0 = __builtin_amdgcn_cvt_pk_fp8_f32(a.x, a.y, 0, false);
    p0 = __builtin_amdgcn_cvt_pk_fp8_f32(a.z, a.w, p0, true);
    int p1 = __builtin_amdgcn_cvt_pk_fp8_f32(b.x, b.y, 0, false);
    p1 = __builtin_amdgcn_cvt_pk_fp8_f32(b.z, b.w, p1, true);
    x8[id] = (uint2){(uint)p0, (uint)p1};
  }
  if (id < HID_DIM * IN_DIM) {             // 8192
    int c = id / IN_DIM, k = id - c * IN_DIM;
    W1T[id] = f2bf(W1[k * HID_DIM + c]);
  }
  if (id < 48 * HID_DIM) {                 // 6144
    int c = id / HID_DIM, k = id - c * HID_DIM;
    W2T[id] = (c < OUT_DIM) ? f2bf(W2[k * OUT_DIM + c]) : 0;
  }
  if (id < MAXNB) gcur[id] = 0;
}

// ------- bucket_scatter: reg-cached edges -> direct write into bucket staging -------

__global__ __launch_bounds__(256) void bucket_scatter(
    const int* __restrict__ src, const int* __restrict__ dst,
    int* __restrict__ gcur, int* __restrict__ epk_s, int n_edges, int nb) {
  __shared__ int hist[MAXNB];
  __shared__ int lofs[MAXNB];
  __shared__ int gbase[MAXNB];
  int tid = threadIdx.x;
  for (int i = tid; i < nb; i += 256) { hist[i] = 0; lofs[i] = 0; }
  __syncthreads();
  int e0 = blockIdx.x * EPB;
  int cnt = min(EPB, n_edges - e0);
  int dr[EPT], sr[EPT];
#pragma unroll
  for (int r = 0; r < EPT; ++r) {        // single read pass, cached in regs
    int i = r * 256 + tid;
    if (i < cnt) {
      dr[r] = dst[e0 + i];
      sr[r] = src[e0 + i];
      atomicAdd(&hist[dr[r] >> BSH], 1);
    } else { dr[r] = -1; sr[r] = 0; }
  }
  __syncthreads();
  for (int i = tid; i < nb; i += 256)
    if (hist[i]) gbase[i] = atomicAdd(&gcur[i], hist[i]);
  __syncthreads();
#pragma unroll
  for (int r = 0; r < EPT; ++r) {        // direct scattered write (short runs/bucket)
    if (dr[r] >= 0) {
      int b = dr[r] >> BSH;
      int p = gbase[b] + atomicAdd(&lofs[b], 1);
      epk_s[b * CAP + p] = ((dr[r] & 255) << 17) | sr[r];   // n_nodes < 2^17
    }
  }
}

// ------- bucket_csr: reg-cached epk -> off2{start,end} + sorted esrc -------

__global__ __launch_bounds__(256) void bucket_csr(
    const int* __restrict__ epk_s, const int* __restrict__ gcnt,
    int2* __restrict__ off2, int* __restrict__ esrc_s, int n_nodes) {
  __shared__ int hist[256];
  __shared__ int cur[256];
  int b = blockIdx.x;
  int base = b * CAP;
  int cnt = gcnt[b];
  int nb0 = b << BSH;
  int nn = min(256, n_nodes - nb0);
  int tid = threadIdx.x;
  hist[tid] = 0;
  __syncthreads();
  int pv[CPT];
#pragma unroll
  for (int r = 0; r < CPT; ++r) {        // single read pass, cached in regs
    int i = r * 256 + tid;
    if (i < cnt) {
      pv[r] = epk_s[base + i];
      atomicAdd(&hist[pv[r] >> 17], 1);
    } else pv[r] = -1;
  }
  __syncthreads();
  if (tid < 64) {  // exclusive scan of 256 entries
    int carry = 0;
#pragma unroll
    for (int c = 0; c < 256; c += 64) {
      int v = hist[c + tid];
      int incl = v;
#pragma unroll
      for (int d = 1; d < 64; d <<= 1) {
        int t = __shfl_up(incl, d, 64);
        if (tid >= d) incl += t;
      }
      cur[c + tid] = carry + incl - v;
      carry += __shfl(incl, 63, 64);
    }
  }
  __syncthreads();
  if (tid < nn) {
    int st = cur[tid];
    off2[nb0 + tid] = make_int2(base + st, base + st + hist[tid]);
  }
  __syncthreads();  // off2 reads cur/hist before scatter mutates cur
#pragma unroll
  for (int r = 0; r < CPT; ++r) {
    if (pv[r] >= 0) {
      int pos = atomicAdd(&cur[pv[r] >> 17], 1);
      esrc_s[base + pos] = pv[r] & 0x1FFFF;
    }
  }
}

// -------- agg1: aggr1h[n] = bf16(x[n] + sum_j x8[j]), 2 nodes/wave, uint2 loads --------
// lane: bit5 = node-select, bits3-4 = edge-slot (4), bits0-2 = uint2 q of 64B row.

__global__ __launch_bounds__(256) void agg1(
    const float4* __restrict__ x4, const uint2* __restrict__ x8,
    const int2* __restrict__ off2, const int* __restrict__ esrc,
    ushort* __restrict__ aggrh, int n_nodes) {
  int tid = threadIdx.x;
  int lane = tid & 63;
  int nsel = (lane >> 5) & 1, es = (lane >> 3) & 3, q = lane & 7;
  int node = blockIdx.x * 8 + (tid >> 6) * 2 + nsel;
  bool nok = node < n_nodes;
  int2 oe = nok ? off2[node] : make_int2(0, 0);
  floatx2 A0 = {0.f, 0.f}, A1 = {0.f, 0.f}, A2 = {0.f, 0.f}, A3 = {0.f, 0.f};
  floatx2 C0 = {0.f, 0.f}, C1 = {0.f, 0.f}, C2 = {0.f, 0.f}, C3 = {0.f, 0.f};
  int e = oe.x, end = oe.y;
  for (; e + 8 <= end; e += 8) {           // 8 edges, 2 loads/lane
    uint2 u0 = x8[(uint)(esrc[e + es] * 8 + q)];
    uint2 u1 = x8[(uint)(esrc[e + 4 + es] * 8 + q)];
    A0 += __builtin_amdgcn_cvt_pk_f32_fp8((int)u0.x, false);
    A1 += __builtin_amdgcn_cvt_pk_f32_fp8((int)u0.x, true);
    A2 += __builtin_amdgcn_cvt_pk_f32_fp8((int)u0.y, false);
    A3 += __builtin_amdgcn_cvt_pk_f32_fp8((int)u0.y, true);
    C0 += __builtin_amdgcn_cvt_pk_f32_fp8((int)u1.x, false);
    C1 += __builtin_amdgcn_cvt_pk_f32_fp8((int)u1.x, true);
    C2 += __builtin_amdgcn_cvt_pk_f32_fp8((int)u1.y, false);
    C3 += __builtin_amdgcn_cvt_pk_f32_fp8((int)u1.y, true);
  }
  for (; e < end; e += 4) {
    int idx = e + es;
    if (idx < end) {
      uint2 u = x8[(uint)(esrc[idx] * 8 + q)];
      A0 += __builtin_amdgcn_cvt_pk_f32_fp8((int)u.x, false);
      A1 += __builtin_amdgcn_cvt_pk_f32_fp8((int)u.x, true);
      A2 += __builtin_amdgcn_cvt_pk_f32_fp8((int)u.y, false);
      A3 += __builtin_amdgcn_cvt_pk_f32_fp8((int)u.y, true);
    }
  }
  A0 += C0; A1 += C1; A2 += C2; A3 += C3;
  // reduce over edge-slot bits 3,4
#pragma unroll
  for (int d = 8; d <= 16; d <<= 1) {
    floatx2 t0, t1, t2, t3;
    t0[0] = __shfl_xor(A0[0], d, 64); t0[1] = __shfl_xor(A0[1], d, 64);
    t1[0] = __shfl_xor(A1[0], d, 64); t1[1] = __shfl_xor(A1[1], d, 64);
    t2[0] = __shfl_xor(A2[0], d, 64); t2[1] = __shfl_xor(A2[1], d, 64);
    t3[0] = __shfl_xor(A3[0], d, 64); t3[1] = __shfl_xor(A3[1], d, 64);
    A0 += t0; A1 += t1; A2 += t2; A3 += t3;
  }
  if (nok) {  // self row (fp32) for features 8q..8q+7
    float4 xa = x4[(uint)(node * 16 + q * 2)];
    float4 xb = x4[(uint)(node * 16 + q * 2 + 1)];
    A0 += (floatx2){xa.x, xa.y};
    A1 += (floatx2){xa.z, xa.w};
    A2 += (floatx2){xb.x, xb.y};
    A3 += (floatx2){xb.z, xb.w};
  }
  if (nok && es == 0) {
    uint4 o;
    o.x = (uint)f2bf(A0[0]) | ((uint)f2bf(A0[1]) << 16);
    o.y = (uint)f2bf(A1[0]) | ((uint)f2bf(A1[1]) << 16);
    o.z = (uint)f2bf(A2[0]) | ((uint)f2bf(A2[1]) << 16);
    o.w = (uint)f2bf(A3[0]) | ((uint)f2bf(A3[1]) << 16);
    ((uint4*)aggrh)[(uint)(node * 8 + q)] = o;
  }
}

// ------- gemm12 (MFMA, fused): th8 = fp8((relu(aggr@W1+b1)) @ W2), h1 in LDS -------

__global__ __launch_bounds__(256) void gemm12_mfma(
    const ushort* __restrict__ aggrh, const ushort* __restrict__ W1T,
    const float* __restrict__ b1, const ushort* __restrict__ W2T,
    uchar* __restrict__ th8, int n_nodes) {
  __shared__ ushort h1s[64 * H1S];
  int w = threadIdx.x >> 6, lane = threadIdx.x & 63;
  int n0 = blockIdx.x * 64 + w * 16;
  int row = lane & 15, kg = lane >> 4;
  int n = n0 + row;
  // ---- layer 1 ----
  {
    short8_t a0 = {}, a1 = {};
    if (n < n_nodes) {
      a0 = *(const short8_t*)&aggrh[(size_t)n * IN_DIM + kg * 8];
      a1 = *(const short8_t*)&aggrh[(size_t)n * IN_DIM + 32 + kg * 8];
    }
    float4_t acc[8];
#pragma unroll
    for (int ct = 0; ct < 8; ++ct) acc[ct] = (float4_t){0.f, 0.f, 0.f, 0.f};
#pragma unroll
    for (int ct = 0; ct < 8; ++ct) {
      int c = ct * 16 + row;
      short8_t b0 = *(const short8_t*)&W1T[(size_t)c * IN_DIM + kg * 8];
      short8_t b1f = *(const short8_t*)&W1T[(size_t)c * IN_DIM + 32 + kg * 8];
      acc[ct] = __builtin_amdgcn_mfma_f32_16x16x32_bf16(a0, b0, acc[ct], 0, 0, 0);
      acc[ct] = __builtin_amdgcn_mfma_f32_16x16x32_bf16(a1, b1f, acc[ct], 0, 0, 0);
    }
#pragma unroll
    for (int ct = 0; ct < 8; ++ct) {
      int j = ct * 16 + row;
      float bias = b1[j];
#pragma unroll
      for (int i = 0; i < 4; ++i) {
        int nl = w * 16 + kg * 4 + i;
        h1s[nl * H1S + j] = f2bf(fmaxf(acc[ct][i] + bias, 0.f));
      }
    }
  }
  __syncthreads();
  // ---- layer 2 (A from LDS h1s) ----
  {
    short8_t a[4];
#pragma unroll
    for (int ks = 0; ks < 4; ++ks)
      a[ks] = *(const short8_t*)&h1s[(w * 16 + row) * H1S + ks * 32 + kg * 8];
    float4_t acc[3];
#pragma unroll
    for (int ct = 0; ct < 3; ++ct) acc[ct] = (float4_t){0.f, 0.f, 0.f, 0.f};
#pragma unroll
    for (int ct = 0; ct < 3; ++ct) {
      int c = ct * 16 + row;
#pragma unroll
      for (int ks = 0; ks < 4; ++ks) {
        short8_t b = *(const short8_t*)&W2T[(size_t)c * HID_DIM + ks * 32 + kg * 8];
        acc[ct] = __builtin_amdgcn_mfma_f32_16x16x32_bf16(a[ks], b, acc[ct], 0, 0, 0);
      }
    }
#pragma unroll
    for (int ct = 0; ct < 3; ++ct) {
      int j = ct * 16 + row;
      if (j < OUT_DIM) {
#pragma unroll
        for (int i = 0; i < 4; ++i) {
          int nn = n0 + kg * 4 + i;
          if (nn < n_nodes) {
            int pk = __builtin_amdgcn_cvt_pk_fp8_f32(acc[ct][i], acc[ct][i], 0, false);
            th8[(size_t)nn * 40 + j] = (uchar)(pk & 0xff);
          }
        }
      }
    }
  }
}

// ------- final: out = log_softmax(t[n] + sum_j t[j] + b2) -------
// per 32-lane half (one node): 6 edge-slots x 5 uint2-q (lanes 30,31 idle).

__global__ __launch_bounds__(256) void final_fused(
    const uchar* __restrict__ th8, const int2* __restrict__ off2,
    const int* __restrict__ esrc, const float* __restrict__ b2,
    float* __restrict__ out, int n_nodes) {
  int tid = threadIdx.x;
  int lane = tid & 63;
  int half = lane >> 5;
  int l5 = lane & 31;
  int es = l5 / 5;                // 0..6 (6 = idle)
  int q = l5 - es * 5;            // 0..4
  int sbase = half * 32;
  int node = blockIdx.x * 8 + (tid >> 6) * 2 + half;
  bool nok = node < n_nodes;
  bool act = nok && (es < 6);
  const uint2* tr2 = (const uint2*)th8;   // row = 5 uint2 (40 B)
  int2 oe = nok ? off2[node] : make_int2(0, 0);
  floatx2 A0 = {0.f, 0.f}, A1 = {0.f, 0.f}, A2 = {0.f, 0.f}, A3 = {0.f, 0.f};
  floatx2 C0 = {0.f, 0.f}, C1 = {0.f, 0.f}, C2 = {0.f, 0.f}, C3 = {0.f, 0.f};
  int e = oe.x, end = oe.y;
  for (; e + 12 <= end; e += 12) {         // 12 edges, 2 uint2 loads/lane
    uint2 u0 = {0, 0}, u1 = {0, 0};
    if (act) {
      u0 = tr2[(uint)(esrc[e + es] * 5 + q)];
      u1 = tr2[(uint)(esrc[e + 6 + es] * 5 + q)];
    }
    A0 += __builtin_amdgcn_cvt_pk_f32_fp8((int)u0.x, false);
    A1 += __builtin_amdgcn_cvt_pk_f32_fp8((int)u0.x, true);
    A2 += __builtin_amdgcn_cvt_pk_f32_fp8((int)u0.y, false);
    A3 += __builtin_amdgcn_cvt_pk_f32_fp8((int)u0.y, true);
    C0 += __builtin_amdgcn_cvt_pk_f32_fp8((int)u1.x, false);
    C1 += __builtin_amdgcn_cvt_pk_f32_fp8((int)u1.x, true);
    C2 += __builtin_amdgcn_cvt_pk_f32_fp8((int)u1.y, false);
    C3 += __builtin_amdgcn_cvt_pk_f32_fp8((int)u1.y, true);
  }
  for (; e < end; e += 6) {
    int idx = e + es;
    if (act && idx < end) {
      uint2 u = tr2[(uint)(esrc[idx] * 5 + q)];
      A0 += __builtin_amdgcn_cvt_pk_f32_fp8((int)u.x, false);
      A1 += __builtin_amdgcn_cvt_pk_f32_fp8((int)u.x, true);
      A2 += __builtin_amdgcn_cvt_pk_f32_fp8((int)u.y, false);
      A3 += __builtin_amdgcn_cvt_pk_f32_fp8((int)u.y, true);
    }
  }
  A0 += C0; A1 += C1; A2 += C2; A3 += C3;
  // slot reduce: slots {0,1,2} += slots {3,4,5}  (same q is +15 lanes away)
  {
    int s1 = sbase + ((l5 + 15) & 31);
    floatx2 t0, t1, t2, t3;
    t0[0] = __shfl(A0[0], s1, 64); t0[1] = __shfl(A0[1], s1, 64);
    t1[0] = __shfl(A1[0], s1, 64); t1[1] = __shfl(A1[1], s1, 64);
    t2[0] = __shfl(A2[0], s1, 64); t2[1] = __shfl(A2[1], s1, 64);
    t3[0] = __shfl(A3[0], s1, 64); t3[1] = __shfl(A3[1], s1, 64);
    if (es < 3) { A0 += t0; A1 += t1; A2 += t2; A3 += t3; }
  }
  // slot 0 += slot 1 (+5) and slot 2 (+10)
  {
    int sA = sbase + ((l5 + 5) & 31);
    int sB = sbase + ((l5 + 10) & 31);
    floatx2 t0, t1, t2, t3, v0, v1, v2, v3;
    t0[0] = __shfl(A0[0], sA, 64); t0[1] = __shfl(A0[1], sA, 64);
    t1[0] = __shfl(A1[0], sA, 64); t1[1] = __shfl(A1[1], sA, 64);
    t2[0] = __shfl(A2[0], sA, 64); t2[1] = __shfl(A2[1], sA, 64);
    t3[0] = __shfl(A3[0], sA, 64); t3[1] = __shfl(A3[1], sA, 64);
    v0[0] = __shfl(A0[0], sB, 64); v0[1] = __shfl(A0[1], sB, 64);
    v1[0] = __shfl(A1[0], sB, 64); v1[1] = __shfl(A1[1], sB, 64);
    v2[0] = __shfl(A2[0], sB, 64); v2[1] = __shfl(A2[1], sB, 64);
    v3[0] = __shfl(A3[0], sB, 64); v3[1] = __shfl(A3[1], sB, 64);
    if (es == 0) {
      A0 += t0 + v0; A1 += t1 + v1; A2 += t2 + v2; A3 += t3 + v3;
    }
  }
  bool own = nok && (es == 0);
  if (own) {  // own row + bias (features 8q..8q+7)
    uint2 uo = tr2[(uint)(node * 5 + q)];
    float4 bb0 = ((const float4*)b2)[2 * q];
    float4 bb1 = ((const float4*)b2)[2 * q + 1];
    A0 += __builtin_amdgcn_cvt_pk_f32_fp8((int)uo.x, false);
    A1 += __builtin_amdgcn_cvt_pk_f32_fp8((int)uo.x, true);
    A2 += __builtin_amdgcn_cvt_pk_f32_fp8((int)uo.y, false);
    A3 += __builtin_amdgcn_cvt_pk_f32_fp8((int)uo.y, true);
    A0 += (floatx2){bb0.x, bb0.y};
    A1 += (floatx2){bb0.z, bb0.w};
    A2 += (floatx2){bb1.x, bb1.y};
    A3 += (floatx2){bb1.z, bb1.w};
  }
  // softmax across 5 q-lanes (lanes sbase..sbase+4) x 8 regs each
  float m = own ? fmaxf(fmaxf(fmaxf(A0[0], A0[1]), fmaxf(A1[0], A1[1])),
                        fmaxf(fmaxf(A2[0], A2[1]), fmaxf(A3[0], A3[1])))
                : -INFINITY;
  float mm = m;
#pragma unroll
  for (int j = 1; j < 5; ++j) {
    int sj = sbase + ((q + j) % 5);
    mm = fmaxf(mm, __shfl(m, sj, 64));
  }
  float s = 0.f;
  if (own)
    s = ((__expf(A0[0] - mm) + __expf(A0[1] - mm)) +
         (__expf(A1[0] - mm) + __expf(A1[1] - mm))) +
        ((__expf(A2[0] - mm) + __expf(A2[1] - mm)) +
         (__expf(A3[0] - mm) + __expf(A3[1] - mm)));
  float st = s;
#pragma unroll
  for (int j = 1; j < 5; ++j) {
    int sj = sbase + ((q + j) % 5);
    st += __shfl(s, sj, 64);
  }
  if (own) {
    float ls = mm + __logf(st);
    float4 o0 = {A0[0] - ls, A0[1] - ls, A1[0] - ls, A1[1] - ls};
    float4 o1 = {A2[0] - ls, A2[1] - ls, A3[0] - ls, A3[1] - ls};
    ((float4*)out)[(uint)(node * 10 + 2 * q)] = o0;
    ((float4*)out)[(uint)(node * 10 + 2 * q + 1)] = o1;
  }
}

// ---------------- launch ----------------

static inline char* align256(char* p) {
  return (char*)(((uintptr_t)p + 255) & ~(uintptr_t)255);
}

extern "C" void kernel_launch(void* const* d_in, const int* in_sizes, int n_in,
                              void* d_out, int out_size, void* d_ws, size_t ws_size,
                              hipStream_t stream) {
  const float* x  = (const float*)d_in[0];
  const int*   ei = (const int*)d_in[1];    // [2][E] int32
  const float* W1 = (const float*)d_in[2];
  const float* b1 = (const float*)d_in[3];
  const float* W2 = (const float*)d_in[4];
  const float* b2 = (const float*)d_in[5];
  float* out = (float*)d_out;

  int n_nodes = in_sizes[0] / IN_DIM;
  int n_edges = in_sizes[1] / 2;
  const int* src = ei;
  const int* dst = ei + n_edges;
  int nb = (n_nodes + 255) >> BSH;

  char* p = (char*)d_ws;
  int* gcur   = (int*)p;            p += MAXNB * 4;
  int2* off2  = (int2*)p;           p += (size_t)n_nodes * 8;
  p = align256(p);
  int* epk_s  = (int*)p;            p += (size_t)nb * CAP * 4;
  int* esrc_s = (int*)p;            p += (size_t)nb * CAP * 4;
  p = align256(p);
  uchar* x8    = (uchar*)p;         p += (size_t)n_nodes * IN_DIM;      // fp8, 64 B rows
  p = align256(p);
  ushort* aggrh = (ushort*)p;       p += (size_t)n_nodes * IN_DIM * 2;
  p = align256(p);
  uchar* th8    = (uchar*)p;        p += (size_t)n_nodes * 40 + 256;    // fp8, 40 B rows
  p = align256(p);
  ushort* W1T   = (ushort*)p;       p += HID_DIM * IN_DIM * 2;          // [128][64]
  ushort* W2T   = (ushort*)p;       p += 48 * HID_DIM * 2;              // [48][128]

  int n8 = n_nodes * IN_DIM / 8;
  prep<<<(n8 + 255) / 256, 256, 0, stream>>>(
      (const float4*)x, (uint2*)x8, n8, W1, W2, W1T, W2T, gcur);

  int egrid = (n_edges + EPB - 1) / EPB;
  bucket_scatter<<<egrid, 256, 0, stream>>>(src, dst, gcur, epk_s, n_edges, nb);
  bucket_csr<<<nb, 256, 0, stream>>>(epk_s, gcur, off2, esrc_s, n_nodes);

  agg1<<<(n_nodes + 7) / 8, 256, 0, stream>>>(
      (const float4*)x, (const uint2*)x8, off2, esrc_s, aggrh, n_nodes);
  int ggrid = (n_nodes + 63) / 64;
  gemm12_mfma<<<ggrid, 256, 0, stream>>>(aggrh, W1T, b1, W2T, th8, n_nodes);
  final_fused<<<(n_nodes + 7) / 8, 256, 0, stream>>>(th8, off2, esrc_s, b2, out, n_nodes);
}